// Round 8
// baseline (909.344 us; speedup 1.0000x reference)
//
#include <hip/hip_runtime.h>

#define IN_CH 500
#define KSTEPS 10

typedef unsigned int u32;
typedef unsigned short u16;
typedef short bf16x8 __attribute__((ext_vector_type(8)));
typedef float f32x4 __attribute__((ext_vector_type(4)));
typedef float f32x2 __attribute__((ext_vector_type(2)));

__device__ __forceinline__ float bf2f(u16 u) {
    union { u32 i; float f; } v; v.i = ((u32)u) << 16; return v.f;
}
__device__ __forceinline__ u16 f2bf(float f) {
    union { float f; u32 i; } v; v.f = f;
    u32 x = v.i;
    return (u16)((x + 0x7FFFu + ((x >> 16) & 1u)) >> 16);  // RNE
}
__device__ __forceinline__ u32 f_as_u(float f) {
    union { float f; u32 i; } v; v.f = f; return v.i;
}
__device__ __forceinline__ float u_as_f(u32 i) {
    union { u32 i; float f; } v; v.i = i; return v.f;
}

// ---------------- runtime dtype detection ----------------
__global__ void detect_kernel(const u16* __restrict__ w1raw,
                              const int* __restrict__ ei,
                              u32* __restrict__ flags) {
    int t = threadIdx.x;  // 64 threads
    float m = fabsf(bf2f(w1raw[t]));
    m = fmaxf(m, fabsf(bf2f(w1raw[64 + t])));
    m = fmaxf(m, fabsf(bf2f(w1raw[128 + t])));
    for (int off = 32; off; off >>= 1) m = fmaxf(m, __shfl_down(m, off));
    u32 o = (u32)ei[2 * t + 1];
    o |= (u32)ei[2 * t + 129];
    for (int off = 32; off; off >>= 1) o |= __shfl_down(o, off);
    if (t == 0) {
        flags[0] = (m > 10.0f) ? 1u : 0u;
        flags[1] = (o == 0u) ? 1u : 0u;
    }
}

// ---------------- W1 transpose + hi/lo split precompute ----------------
__global__ void w1t_kernel(const void* __restrict__ W1v,
                           u16* __restrict__ hi, u16* __restrict__ lo,
                           const u32* __restrict__ flags) {
    int i = blockIdx.x * 256 + threadIdx.x;   // 0 .. 32767
    if (i >= 64 * 512) return;
    int h = i >> 9;
    int k = i & 511;
    u16 vh = 0, vl = 0;
    if (k < IN_CH) {
        if (flags[0]) {
            float v = ((const float*)W1v)[(size_t)k * 64 + h];
            u32 bits = f_as_u(v);
            vh = (u16)(bits >> 16);
            float d = v - u_as_f(bits & 0xFFFF0000u);
            vl = (u16)(f_as_u(d) >> 16);
        } else {
            vh = ((const u16*)W1v)[(size_t)k * 64 + h];
        }
    }
    hi[(size_t)h * 512 + k] = vh;
    lo[(size_t)h * 512 + k] = vl;
}

// ---------------- MLP, f32 storage: split-bf16 MFMA path ----------------
__global__ __launch_bounds__(512) void mlp_mfma_f32(
    const float* __restrict__ xf, const u16* __restrict__ w1hig,
    const u16* __restrict__ w1log, const float* __restrict__ b1f,
    const float* __restrict__ W2f, const float* __restrict__ b2f,
    const float* __restrict__ dinv, float* __restrict__ h0,
    float* __restrict__ gout, const u32* __restrict__ flags, int N)
{
    if (flags[0] == 0u) return;          // bf16 storage -> mlp_mfma_kernel

    __shared__ __align__(16) u16 w1hi[64 * 520];
    __shared__ __align__(16) u16 w1lo[64 * 520];
    __shared__ float w2s[64][16];
    __shared__ float b1s[64];
    __shared__ float b2s[16];
    float* hh = (float*)w1hi;            // aliased after K-loop: [64][130]

    const int t = threadIdx.x;
    const int w = t >> 6;                // wave 0..7
    const int l = t & 63;
    const int ln = l & 15;               // node within wave tile
    const int g = l >> 4;                // k-subgroup 0..3
    const int nodeBase = blockIdx.x * 128;

    for (int i = t; i < 1024; i += 512) w2s[i >> 4][i & 15] = W2f[i];
    if (t < 64) b1s[t] = b1f[t];
    if (t < 16) b2s[t] = b2f[t];

#pragma unroll
    for (int i = 0; i < 8; ++i) {
        int c = t + i * 512;
        int row = c >> 6, c8 = c & 63;
        *(bf16x8*)&w1hi[row * 520 + c8 * 8] =
            *(const bf16x8*)(w1hig + (size_t)row * 512 + c8 * 8);
        *(bf16x8*)&w1lo[row * 520 + c8 * 8] =
            *(const bf16x8*)(w1log + (size_t)row * 512 + c8 * 8);
    }
    __syncthreads();

    const int node = nodeBase + w * 16 + ln;
    const bool nv = (node < N);
    const float* xrow = xf + (size_t)node * IN_CH;

    f32x4 acc0 = {0.f, 0.f, 0.f, 0.f};
    f32x4 acc1 = {0.f, 0.f, 0.f, 0.f};
    f32x4 acc2 = {0.f, 0.f, 0.f, 0.f};
    f32x4 acc3 = {0.f, 0.f, 0.f, 0.f};

#pragma unroll
    for (int ki = 0; ki < 16; ++ki) {
        const int kb = ki * 32 + g * 8;
        float xv[8];
#pragma unroll
        for (int e = 0; e < 8; ++e) xv[e] = 0.f;
        if (nv) {
            if (kb + 8 <= IN_CH) {
                float4 v0 = *(const float4*)(xrow + kb);
                float4 v1 = *(const float4*)(xrow + kb + 4);
                xv[0] = v0.x; xv[1] = v0.y; xv[2] = v0.z; xv[3] = v0.w;
                xv[4] = v1.x; xv[5] = v1.y; xv[6] = v1.z; xv[7] = v1.w;
            } else if (kb < IN_CH) {
                float4 v0 = *(const float4*)(xrow + kb);
                xv[0] = v0.x; xv[1] = v0.y; xv[2] = v0.z; xv[3] = v0.w;
            }
        }
        bf16x8 bh, bl;
#pragma unroll
        for (int e = 0; e < 8; ++e) {
            u32 bits = f_as_u(xv[e]);
            bh[e] = (short)(bits >> 16);
            float d = xv[e] - u_as_f(bits & 0xFFFF0000u);
            bl[e] = (short)(f_as_u(d) >> 16);
        }
        const u16* ph = &w1hi[ln * 520 + kb];
        const u16* pl = &w1lo[ln * 520 + kb];
        bf16x8 ah0 = *(const bf16x8*)(ph);
        bf16x8 ah1 = *(const bf16x8*)(ph + 16 * 520);
        bf16x8 ah2 = *(const bf16x8*)(ph + 32 * 520);
        bf16x8 ah3 = *(const bf16x8*)(ph + 48 * 520);
        bf16x8 al0 = *(const bf16x8*)(pl);
        bf16x8 al1 = *(const bf16x8*)(pl + 16 * 520);
        bf16x8 al2 = *(const bf16x8*)(pl + 32 * 520);
        bf16x8 al3 = *(const bf16x8*)(pl + 48 * 520);
        acc0 = __builtin_amdgcn_mfma_f32_16x16x32_bf16(ah0, bh, acc0, 0, 0, 0);
        acc1 = __builtin_amdgcn_mfma_f32_16x16x32_bf16(ah1, bh, acc1, 0, 0, 0);
        acc2 = __builtin_amdgcn_mfma_f32_16x16x32_bf16(ah2, bh, acc2, 0, 0, 0);
        acc3 = __builtin_amdgcn_mfma_f32_16x16x32_bf16(ah3, bh, acc3, 0, 0, 0);
        acc0 = __builtin_amdgcn_mfma_f32_16x16x32_bf16(al0, bh, acc0, 0, 0, 0);
        acc1 = __builtin_amdgcn_mfma_f32_16x16x32_bf16(al1, bh, acc1, 0, 0, 0);
        acc2 = __builtin_amdgcn_mfma_f32_16x16x32_bf16(al2, bh, acc2, 0, 0, 0);
        acc3 = __builtin_amdgcn_mfma_f32_16x16x32_bf16(al3, bh, acc3, 0, 0, 0);
        acc0 = __builtin_amdgcn_mfma_f32_16x16x32_bf16(ah0, bl, acc0, 0, 0, 0);
        acc1 = __builtin_amdgcn_mfma_f32_16x16x32_bf16(ah1, bl, acc1, 0, 0, 0);
        acc2 = __builtin_amdgcn_mfma_f32_16x16x32_bf16(ah2, bl, acc2, 0, 0, 0);
        acc3 = __builtin_amdgcn_mfma_f32_16x16x32_bf16(ah3, bl, acc3, 0, 0, 0);
    }
    __syncthreads();    // all waves done reading w1hi; reuse it as hh

    const int nl = w * 16 + ln;
    const int rb = g * 4;
#pragma unroll
    for (int r = 0; r < 4; ++r) {
        float v0 = acc0[r] + b1s[rb + r];
        float v1 = acc1[r] + b1s[16 + rb + r];
        float v2 = acc2[r] + b1s[32 + rb + r];
        float v3 = acc3[r] + b1s[48 + rb + r];
        hh[(rb + r) * 130 + nl]      = v0 > 0.f ? v0 : 0.f;
        hh[(16 + rb + r) * 130 + nl] = v1 > 0.f ? v1 : 0.f;
        hh[(32 + rb + r) * 130 + nl] = v2 > 0.f ? v2 : 0.f;
        hh[(48 + rb + r) * 130 + nl] = v3 > 0.f ? v3 : 0.f;
    }
    __syncthreads();

    {
        int n = t >> 2;                  // 0..127
        int o4 = (t & 3) * 4;
        float o0 = b2s[o4], o1 = b2s[o4 + 1], o2 = b2s[o4 + 2], o3 = b2s[o4 + 3];
#pragma unroll
        for (int j = 0; j < 64; ++j) {
            float hv = hh[j * 130 + n];
            o0 += hv * w2s[j][o4];     o1 += hv * w2s[j][o4 + 1];
            o2 += hv * w2s[j][o4 + 2]; o3 += hv * w2s[j][o4 + 3];
        }
        int gn = nodeBase + n;
        if (gn < N) {
            float4 o = {o0, o1, o2, o3};
            *(float4*)(h0 + (size_t)gn * 16 + o4) = o;
            float dn = dinv[gn];
            float4 gg = {o0 * dn, o1 * dn, o2 * dn, o3 * dn};
            *(float4*)(gout + (size_t)gn * 16 + o4) = gg;
        }
    }
}

// ---------------- MLP, bf16 storage: MFMA path (hi array only) ----------------
__global__ __launch_bounds__(256) void mlp_mfma_kernel(
    const u16* __restrict__ xh, const u16* __restrict__ w1tg,
    const void* __restrict__ b1v, const void* __restrict__ W2v,
    const void* __restrict__ b2v, const float* __restrict__ dinv,
    float* __restrict__ h0, float* __restrict__ gout,
    const u32* __restrict__ flags, int N)
{
    if (flags[0] != 0u) return;          // f32 storage -> mlp_mfma_f32

    __shared__ __align__(16) u16 w1s[64 * 520];
    __shared__ float w2s[64][16];
    __shared__ float b1s[64];
    __shared__ float b2s[16];
    float* hh = (float*)w1s;

    const u16* b1h = (const u16*)b1v;
    const u16* W2h = (const u16*)W2v;
    const u16* b2h = (const u16*)b2v;

    const int t = threadIdx.x;
    const int w = t >> 6;
    const int l = t & 63;
    const int ln = l & 15;
    const int g = l >> 4;
    const int nodeBase = blockIdx.x * 64;

    for (int i = t; i < 1024; i += 256) w2s[i >> 4][i & 15] = bf2f(W2h[i]);
    if (t < 64) b1s[t] = bf2f(b1h[t]);
    if (t < 16) b2s[t] = bf2f(b2h[t]);

#pragma unroll
    for (int i = 0; i < 16; ++i) {
        int idx = t + i * 256;
        int row = idx >> 6, c8 = idx & 63;
        *(bf16x8*)&w1s[row * 520 + c8 * 8] =
            *(const bf16x8*)(w1tg + (size_t)row * 512 + c8 * 8);
    }
    __syncthreads();

    const int node = nodeBase + w * 16 + ln;
    const bool nv = (node < N);
    const u16* xrow = xh + (size_t)node * IN_CH;

    f32x4 acc0 = {0.f, 0.f, 0.f, 0.f};
    f32x4 acc1 = {0.f, 0.f, 0.f, 0.f};
    f32x4 acc2 = {0.f, 0.f, 0.f, 0.f};
    f32x4 acc3 = {0.f, 0.f, 0.f, 0.f};

#pragma unroll
    for (int ki = 0; ki < 15; ++ki) {
        const int kb = ki * 32 + g * 8;
        bf16x8 b = {0, 0, 0, 0, 0, 0, 0, 0};
        if (nv) b = *(const bf16x8*)(xrow + kb);
        const u16* wp = &w1s[ln * 520 + kb];
        bf16x8 a0 = *(const bf16x8*)(wp);
        bf16x8 a1 = *(const bf16x8*)(wp + 16 * 520);
        bf16x8 a2 = *(const bf16x8*)(wp + 32 * 520);
        bf16x8 a3 = *(const bf16x8*)(wp + 48 * 520);
        acc0 = __builtin_amdgcn_mfma_f32_16x16x32_bf16(a0, b, acc0, 0, 0, 0);
        acc1 = __builtin_amdgcn_mfma_f32_16x16x32_bf16(a1, b, acc1, 0, 0, 0);
        acc2 = __builtin_amdgcn_mfma_f32_16x16x32_bf16(a2, b, acc2, 0, 0, 0);
        acc3 = __builtin_amdgcn_mfma_f32_16x16x32_bf16(a3, b, acc3, 0, 0, 0);
    }
    {
        const int kb = 480 + g * 8;
        bf16x8 b = {0, 0, 0, 0, 0, 0, 0, 0};
        if (nv) {
            if (g < 2) {
                b = *(const bf16x8*)(xrow + kb);
            } else if (g == 2) {
                ushort4 v4 = *(const ushort4*)(xrow + 496);
                b[0] = (short)v4.x; b[1] = (short)v4.y;
                b[2] = (short)v4.z; b[3] = (short)v4.w;
            }
        }
        const u16* wp = &w1s[ln * 520 + kb];
        bf16x8 a0 = *(const bf16x8*)(wp);
        bf16x8 a1 = *(const bf16x8*)(wp + 16 * 520);
        bf16x8 a2 = *(const bf16x8*)(wp + 32 * 520);
        bf16x8 a3 = *(const bf16x8*)(wp + 48 * 520);
        acc0 = __builtin_amdgcn_mfma_f32_16x16x32_bf16(a0, b, acc0, 0, 0, 0);
        acc1 = __builtin_amdgcn_mfma_f32_16x16x32_bf16(a1, b, acc1, 0, 0, 0);
        acc2 = __builtin_amdgcn_mfma_f32_16x16x32_bf16(a2, b, acc2, 0, 0, 0);
        acc3 = __builtin_amdgcn_mfma_f32_16x16x32_bf16(a3, b, acc3, 0, 0, 0);
    }
    __syncthreads();

    const int nl = w * 16 + ln;
    const int rb = g * 4;
#pragma unroll
    for (int r = 0; r < 4; ++r) {
        float v0 = acc0[r] + b1s[rb + r];
        float v1 = acc1[r] + b1s[16 + rb + r];
        float v2 = acc2[r] + b1s[32 + rb + r];
        float v3 = acc3[r] + b1s[48 + rb + r];
        hh[(rb + r) * 65 + nl]      = v0 > 0.f ? v0 : 0.f;
        hh[(16 + rb + r) * 65 + nl] = v1 > 0.f ? v1 : 0.f;
        hh[(32 + rb + r) * 65 + nl] = v2 > 0.f ? v2 : 0.f;
        hh[(48 + rb + r) * 65 + nl] = v3 > 0.f ? v3 : 0.f;
    }
    __syncthreads();

    {
        int n = t >> 2;
        int o4 = (t & 3) * 4;
        float o0 = b2s[o4], o1 = b2s[o4 + 1], o2 = b2s[o4 + 2], o3 = b2s[o4 + 3];
#pragma unroll
        for (int j = 0; j < 64; ++j) {
            float hv = hh[j * 65 + n];
            o0 += hv * w2s[j][o4];     o1 += hv * w2s[j][o4 + 1];
            o2 += hv * w2s[j][o4 + 2]; o3 += hv * w2s[j][o4 + 3];
        }
        int gn = nodeBase + n;
        if (gn < N) {
            float4 o = {o0, o1, o2, o3};
            *(float4*)(h0 + (size_t)gn * 16 + o4) = o;
            float dn = dinv[gn];
            float4 gg = {o0 * dn, o1 * dn, o2 * dn, o3 * dn};
            *(float4*)(gout + (size_t)gn * 16 + o4) = gg;
        }
    }
}

// ---------------- graph preprocessing ----------------
__global__ void zero_u32(u32* __restrict__ p, int n) {
    int i = blockIdx.x * 256 + threadIdx.x;
    if (i < n) p[i] = 0u;
}

__device__ __forceinline__ int ei_src(const int* ei, int E, int e, int i64) {
    return i64 ? ei[2 * e] : ei[e];
}
__device__ __forceinline__ int ei_dst(const int* ei, int E, int e, int i64) {
    return i64 ? ei[2 * (E + e)] : ei[E + e];
}

// -------- fallback-path kernels (non-bucket) --------
__global__ void deg_kernel(const int* __restrict__ ei, int E, u32* __restrict__ cnt,
                           const u32* __restrict__ flags) {
    int e = blockIdx.x * 256 + threadIdx.x;
    int i64 = (int)flags[1];
    if (e < E) atomicAdd(&cnt[ei_dst(ei, E, e, i64)], 1u);
}

__global__ void dinv_kernel(const u32* __restrict__ cnt, float* __restrict__ dinv, int N) {
    int i = blockIdx.x * 256 + threadIdx.x;
    if (i < N) {
        float d = (float)(cnt[i] + 1u);      // +1 self-loop
        dinv[i] = rsqrtf(d);
    }
}

__global__ __launch_bounds__(256) void scan1(const u32* __restrict__ cnt,
                                             u32* __restrict__ part, int N) {
    __shared__ u32 s[256];
    int i = blockIdx.x * 256 + threadIdx.x;
    s[threadIdx.x] = (i < N) ? cnt[i] : 0u;
    __syncthreads();
    for (int off = 128; off > 0; off >>= 1) {
        if (threadIdx.x < off) s[threadIdx.x] += s[threadIdx.x + off];
        __syncthreads();
    }
    if (threadIdx.x == 0) part[blockIdx.x] = s[0];
}

__global__ __launch_bounds__(512) void scan2(u32* __restrict__ part,
                                             u32* __restrict__ rowptr, int NB, int N) {
    __shared__ u32 s[512];
    int t = threadIdx.x;
    u32 v = (t < NB) ? part[t] : 0u;
    s[t] = v;
    __syncthreads();
    for (int off = 1; off < 512; off <<= 1) {
        u32 xv = (t >= off) ? s[t - off] : 0u;
        __syncthreads();
        s[t] += xv;
        __syncthreads();
    }
    if (t < NB) part[t] = s[t] - v;          // exclusive block offsets
    if (t == 511) rowptr[N] = s[511];        // total = E
}

__global__ __launch_bounds__(256) void scan3(const u32* __restrict__ cnt,
                                             const u32* __restrict__ part,
                                             u32* __restrict__ rowptr, int N) {
    __shared__ u32 s[256];
    int t = threadIdx.x;
    int i = blockIdx.x * 256 + t;
    u32 v = (i < N) ? cnt[i] : 0u;
    s[t] = v;
    __syncthreads();
    for (int off = 1; off < 256; off <<= 1) {
        u32 xv = (t >= off) ? s[t - off] : 0u;
        __syncthreads();
        s[t] += xv;
        __syncthreads();
    }
    if (i < N) rowptr[i] = part[blockIdx.x] + s[t] - v;
}

#define FILL_BPG 128
__global__ __launch_bounds__(256) void fill_kernel(
    const int* __restrict__ ei, int E,
    const u32* __restrict__ rowptr, u32* __restrict__ fillc,
    u32* __restrict__ ent, const u32* __restrict__ flags, int N)
{
    const int group = blockIdx.x & 7;
    const int bchunk = blockIdx.x >> 3;
    const int gsz = (N + 7) / 8;
    const int lo = group * gsz;
    const int hi = (lo + gsz < N) ? lo + gsz : N;
    const int i64 = (int)flags[1];
    const int stride = FILL_BPG * 256;
    for (int e = bchunk * 256 + (int)threadIdx.x; e < E; e += stride) {
        int c = ei_dst(ei, E, e, i64);
        if (c >= lo && c < hi) {
            int r = ei_src(ei, E, e, i64);
            u32 p = rowptr[c] + atomicAdd(&fillc[c], 1u);
            ent[p] = (u32)r;
        }
    }
}

// ---------------- bucket-path CSR build, atomics-minimized ----------------
#define GSZ_SHIFT 9
#define GSZ 512
#define MAXBUCK 1024
#define CHUNK 4096

__global__ __launch_bounds__(256) void histA(
    const int* __restrict__ ei, int E, int nbuck,
    u32* __restrict__ bcnt, const u32* __restrict__ flags)
{
    __shared__ u32 lb[MAXBUCK];
    const int i64 = (int)flags[1];
    for (int b = threadIdx.x; b < nbuck; b += 256) lb[b] = 0u;
    __syncthreads();
    const int stride = gridDim.x * 256;
    for (int e = blockIdx.x * 256 + (int)threadIdx.x; e < E; e += stride) {
        u32 d = (u32)ei_dst(ei, E, e, i64);
        atomicAdd(&lb[d >> GSZ_SHIFT], 1u);
    }
    __syncthreads();
    for (int b = threadIdx.x; b < nbuck; b += 256)
        if (lb[b]) atomicAdd(&bcnt[b], lb[b]);
}

__global__ __launch_bounds__(1024) void scanB(
    const u32* __restrict__ bcnt, u32* __restrict__ bbase, u32* __restrict__ bf,
    u32* __restrict__ rowptr, int nbuck, int N, int E)
{
    __shared__ u32 s[MAXBUCK];
    int t = threadIdx.x;
    u32 v = (t < nbuck) ? bcnt[t] : 0u;
    s[t] = v;
    __syncthreads();
    for (int off = 1; off < MAXBUCK; off <<= 1) {
        u32 xv = (t >= off) ? s[t - off] : 0u;
        __syncthreads();
        s[t] += xv;
        __syncthreads();
    }
    if (t < nbuck) {
        u32 excl = s[t] - v;
        bbase[t] = excl;
        bf[t] = excl;
    }
    if (t == 0) { bbase[nbuck] = (u32)E; rowptr[N] = (u32)E; }
}

__global__ __launch_bounds__(256) void bucketA(
    const int* __restrict__ ei, int E, int shiftN, int nbuck,
    u32* __restrict__ tmp, u32* __restrict__ bf, const u32* __restrict__ flags)
{
    __shared__ u32 wbuf[CHUNK];
    __shared__ u16 bbuf[CHUNK];
    __shared__ u32 cnt[MAXBUCK], gbase[MAXBUCK], lcnt[MAXBUCK];
    const int i64 = (int)flags[1];
    for (int base = blockIdx.x * CHUNK; base < E; base += gridDim.x * CHUNK) {
        int nval = E - base; if (nval > CHUNK) nval = CHUNK;
        for (int b = threadIdx.x; b < nbuck; b += 256) { cnt[b] = 0u; lcnt[b] = 0u; }
        __syncthreads();
        for (int j = threadIdx.x; j < nval; j += 256) {
            int e = base + j;
            u32 s = (u32)ei_src(ei, E, e, i64);
            u32 d = (u32)ei_dst(ei, E, e, i64);
            u32 b = d >> GSZ_SHIFT;
            wbuf[j] = s | ((d & (GSZ - 1u)) << shiftN);
            bbuf[j] = (u16)b;
            atomicAdd(&cnt[b], 1u);
        }
        __syncthreads();
        for (int b = threadIdx.x; b < nbuck; b += 256)
            if (cnt[b]) gbase[b] = atomicAdd(&bf[b], cnt[b]);
        __syncthreads();
        for (int j = threadIdx.x; j < nval; j += 256) {
            u32 b = (u32)bbuf[j];
            u32 off = atomicAdd(&lcnt[b], 1u);
            tmp[gbase[b] + off] = wbuf[j];
        }
        __syncthreads();
    }
}

__global__ __launch_bounds__(512) void bucketB2(
    const u32* __restrict__ tmp, const u32* __restrict__ bbase,
    u32* __restrict__ rowptr, float* __restrict__ dinv,
    u32* __restrict__ ent, int N, int shiftN)
{
    __shared__ u32 deg[GSZ];
    __shared__ u32 rp[GSZ];
    __shared__ u32 lfill[GSZ];
    const int b = blockIdx.x;
    const int lo = b << GSZ_SHIFT;
    int hi = lo + GSZ; if (hi > N) hi = N;
    const int nn = hi - lo;
    if (nn <= 0) return;
    const u32 base = bbase[b], bend = bbase[b + 1];
    const int t = threadIdx.x;
    deg[t] = 0u; lfill[t] = 0u;
    __syncthreads();
    const u32 mask = (1u << shiftN) - 1u;
    for (u32 p = base + t; p < bend; p += 512)
        atomicAdd(&deg[tmp[p] >> shiftN], 1u);
    __syncthreads();
    u32 v = (t < nn) ? deg[t] : 0u;
    if (t < nn) dinv[lo + t] = rsqrtf((float)(v + 1u));
    rp[t] = v;
    __syncthreads();
    for (int off = 1; off < GSZ; off <<= 1) {
        u32 xv = (t >= off) ? rp[t - off] : 0u;
        __syncthreads();
        rp[t] += xv;
        __syncthreads();
    }
    u32 myrp = base + rp[t] - v;         // exclusive scan + bucket base
    __syncthreads();
    rp[t] = myrp;
    if (t < nn) rowptr[lo + t] = myrp;
    __syncthreads();
    for (u32 p = base + t; p < bend; p += 512) {
        u32 wd = tmp[p];
        u32 src = wd & mask;
        u32 dl = wd >> shiftN;
        u32 pos = rp[dl] + atomicAdd(&lfill[dl], 1u);
        ent[pos] = src;
    }
}

// ---------------- APPNP pull step on scaled state g = D^-1/2 h ----------------
// Wave per node, 8 edge-slots x 8 channel-lanes (float2): per 32-edge chunk
// each lane issues 4 INDEPENDENT idx loads + 4 independent float2 gathers
// (4-deep MLP; avg deg 32 -> exactly one chunk, no clamp waste). Each 64B
// gcur row is consumed fully by 8 lanes x 8B. Reduce over edge-slots via
// 3x shfl_xor(8/16/32); lanes 0..7 do a float2 epilogue.
__global__ __launch_bounds__(256) void prop_kernel(
    const u32* __restrict__ ent, const u32* __restrict__ rowptr,
    const float* __restrict__ dinv, const float* __restrict__ gcur,
    const float* __restrict__ h0, float* __restrict__ gnext,
    void* __restrict__ outp, const u32* __restrict__ flags, int N)
{
    const int t = threadIdx.x;
    const int wv = t >> 6;               // wave 0..3 in block
    const int l = t & 63;
    const int eg = l >> 3;               // edge slot 0..7
    const int c2 = (l & 7) * 2;          // channel pair base
    const int n = blockIdx.x * 4 + wv;
    if (n >= N) return;

    const u32 rs = rowptr[n], re = rowptr[n + 1];
    f32x2 a0 = {0.f, 0.f}, a1 = {0.f, 0.f}, a2 = {0.f, 0.f}, a3 = {0.f, 0.f};
    for (u32 base = rs; base < re; base += 32) {
        u32 pA = base + (u32)eg;
        u32 pB = pA + 8u;
        u32 pC = pA + 16u;
        u32 pD = pA + 24u;
        u32 iA = ent[pA < re ? pA : re - 1u];   // re > rs inside loop
        u32 iB = ent[pB < re ? pB : re - 1u];
        u32 iC = ent[pC < re ? pC : re - 1u];
        u32 iD = ent[pD < re ? pD : re - 1u];
        f32x2 vA = *(const f32x2*)(gcur + (size_t)iA * 16 + c2);
        f32x2 vB = *(const f32x2*)(gcur + (size_t)iB * 16 + c2);
        f32x2 vC = *(const f32x2*)(gcur + (size_t)iC * 16 + c2);
        f32x2 vD = *(const f32x2*)(gcur + (size_t)iD * 16 + c2);
        if (pA < re) a0 += vA;
        if (pB < re) a1 += vB;
        if (pC < re) a2 += vC;
        if (pD < re) a3 += vD;
    }
    f32x2 s = (a0 + a1) + (a2 + a3);
    s[0] += __shfl_xor(s[0], 8);  s[1] += __shfl_xor(s[1], 8);
    s[0] += __shfl_xor(s[0], 16); s[1] += __shfl_xor(s[1], 16);
    s[0] += __shfl_xor(s[0], 32); s[1] += __shfl_xor(s[1], 32);

    if (eg == 0) {                        // lanes 0..7
        f32x2 self = *(const f32x2*)(gcur + (size_t)n * 16 + c2);
        f32x2 h0v  = *(const f32x2*)(h0 + (size_t)n * 16 + c2);
        float dn = dinv[n];
        f32x2 h;
        h[0] = 0.9f * dn * (s[0] + self[0]) + 0.1f * h0v[0];
        h[1] = 0.9f * dn * (s[1] + self[1]) + 0.1f * h0v[1];
        if (gnext) {
            f32x2 gg = {dn * h[0], dn * h[1]};
            *(f32x2*)(gnext + (size_t)n * 16 + c2) = gg;
        } else if (flags[0]) {
            *(f32x2*)((float*)outp + (size_t)n * 16 + c2) = h;
        } else {
            u32 o = (u32)f2bf(h[0]) | ((u32)f2bf(h[1]) << 16);
            *(u32*)((u16*)outp + (size_t)n * 16 + c2) = o;
        }
    }
}

extern "C" void kernel_launch(void* const* d_in, const int* in_sizes, int n_in,
                              void* d_out, int out_size, void* d_ws, size_t ws_size,
                              hipStream_t stream) {
    const void* x  = d_in[0];
    const int* ei  = (const int*)d_in[1];
    const void* W1 = d_in[2];
    const void* b1 = d_in[3];
    const void* W2 = d_in[4];
    const void* b2 = d_in[5];

    const int N = in_sizes[0] / IN_CH;     // 100000
    const int E = in_sizes[1] / 2;         // 3200000

    float* wf = (float*)d_ws;
    u32*   wu = (u32*)d_ws;

    // workspace layout (4B units)
    size_t oH0   = 0;
    size_t oGA   = oH0 + (size_t)N * 16;
    size_t oGB   = oGA + (size_t)N * 16;
    size_t oCNT  = oGB + (size_t)N * 16;
    size_t oFILL = oCNT + N;
    size_t oDINV = oFILL + N;
    size_t oRP   = oDINV + N;
    size_t oPART = ((oRP + N + 1 + 3) & ~(size_t)3);
    size_t oFLG  = oPART + 512;
    size_t oENT  = oFLG + 4;
    size_t oTMP  = oENT + E;              // bucket staging (E words)
    size_t oBF   = oTMP + E;              // bucket append cursors
    size_t oBC   = oBF + MAXBUCK;         // bucket counts
    size_t oBB   = oBC + MAXBUCK;         // bucket bases (nbuck+1)

    int nbuck = (N + GSZ - 1) >> GSZ_SHIFT;
    int shiftN = 1; while ((1 << shiftN) < N && shiftN < 31) shiftN++;
    bool canBucket = (ws_size >= (oBB + MAXBUCK + 1) * 4) &&
                     (shiftN + GSZ_SHIFT <= 32) && (nbuck <= MAXBUCK);

    // W1T hi/lo scratch (128 KB) overlaid on oGB (dead until prop step 1)
    u16* w1hig = (u16*)(wf + oGB);
    u16* w1log = w1hig + 64 * 512;

    detect_kernel<<<1, 64, 0, stream>>>((const u16*)W1, ei, wu + oFLG);
    w1t_kernel<<<128, 256, 0, stream>>>(W1, w1hig, w1log, wu + oFLG);

    if (canBucket) {
        zero_u32<<<(MAXBUCK + 255) / 256, 256, 0, stream>>>(wu + oBC, MAXBUCK);
        histA<<<512, 256, 0, stream>>>(ei, E, nbuck, wu + oBC, wu + oFLG);
        scanB<<<1, 1024, 0, stream>>>(wu + oBC, wu + oBB, wu + oBF,
                                      wu + oRP, nbuck, N, E);
        int nblkA = (E + CHUNK - 1) / CHUNK;
        bucketA<<<nblkA, 256, 0, stream>>>(ei, E, shiftN, nbuck,
                                           wu + oTMP, wu + oBF, wu + oFLG);
        bucketB2<<<nbuck, 512, 0, stream>>>(wu + oTMP, wu + oBB, wu + oRP,
                                            wf + oDINV, wu + oENT, N, shiftN);
    } else {
        zero_u32<<<(2 * N + 255) / 256, 256, 0, stream>>>(wu + oCNT, 2 * N);
        deg_kernel<<<(E + 255) / 256, 256, 0, stream>>>(ei, E, wu + oCNT,
                                                        wu + oFLG);
        dinv_kernel<<<(N + 255) / 256, 256, 0, stream>>>(wu + oCNT,
                                                         wf + oDINV, N);
        int NB = (N + 255) / 256;
        scan1<<<NB, 256, 0, stream>>>(wu + oCNT, wu + oPART, N);
        scan2<<<1, 512, 0, stream>>>(wu + oPART, wu + oRP, NB, N);
        scan3<<<NB, 256, 0, stream>>>(wu + oCNT, wu + oPART, wu + oRP, N);
        fill_kernel<<<8 * FILL_BPG, 256, 0, stream>>>(ei, E, wu + oRP,
                                                      wu + oFILL, wu + oENT,
                                                      wu + oFLG, N);
    }

    mlp_mfma_f32<<<(N + 127) / 128, 512, 0, stream>>>(
        (const float*)x, w1hig, w1log, (const float*)b1, (const float*)W2,
        (const float*)b2, wf + oDINV, wf + oH0, wf + oGA, wu + oFLG, N);
    mlp_mfma_kernel<<<(N + 63) / 64, 256, 0, stream>>>(
        (const u16*)x, w1hig, b1, W2, b2, wf + oDINV, wf + oH0, wf + oGA,
        wu + oFLG, N);

    const float* cur = wf + oGA;
    for (int k = 0; k < KSTEPS; ++k) {
        bool last = (k == KSTEPS - 1);
        float* nxt = last ? nullptr : (wf + ((k & 1) ? oGA : oGB));
        prop_kernel<<<(N + 3) / 4, 256, 0, stream>>>(
            wu + oENT, wu + oRP, wf + oDINV, cur, wf + oH0,
            nxt, last ? d_out : nullptr, wu + oFLG, N);
        if (!last) cur = nxt;
    }
}